// Round 4
// baseline (307.828 us; speedup 1.0000x reference)
//
#include <hip/hip_runtime.h>
#include <hip/hip_bf16.h>
#include <float.h>

#define H 2048
#define E 64
#define TOPK 8
#define TT 8     // tokens per block (fallback fused kernel)
#define NT 512   // threads per block (fallback fused kernel)

typedef __attribute__((ext_vector_type(8))) short bf16x8;
typedef __attribute__((ext_vector_type(4))) float f32x4;
typedef __attribute__((ext_vector_type(4))) unsigned short us4;

__device__ __forceinline__ unsigned short f2bf(float f) {
  unsigned u = __float_as_uint(f);
  u += 0x7fffu + ((u >> 16) & 1u);   // RNE
  return (unsigned short)(u >> 16);
}
__device__ __forceinline__ float bf2f(unsigned short s) {
  return __uint_as_float(((unsigned)s) << 16);
}
__device__ __forceinline__ float wred_max(float v) {
#pragma unroll
  for (int o = 32; o > 0; o >>= 1) v = fmaxf(v, __shfl_xor(v, o));
  return v;
}
__device__ __forceinline__ float wred_sum(float v) {
#pragma unroll
  for (int o = 32; o > 0; o >>= 1) v += __shfl_xor(v, o);
  return v;
}

// Convert router_weight and expert_bias fp32 -> bf16 into workspace (L2-resident).
__global__ __launch_bounds__(256) void cvt_kernel(const float* __restrict__ W,
                                                  const float* __restrict__ eb,
                                                  unsigned short* __restrict__ Wb,
                                                  unsigned short* __restrict__ Bb) {
  int i = (blockIdx.x * 256 + threadIdx.x) * 4;
  const float* src;
  unsigned short* dst;
  int off;
  if (i < E * H) { src = W; dst = Wb; off = i; }
  else           { src = eb; dst = Bb; off = i - E * H; }
  float4 v = *(const float4*)(src + off);
  us4 r;
  r[0] = f2bf(v.x); r[1] = f2bf(v.y); r[2] = f2bf(v.z); r[3] = f2bf(v.w);
  *(us4*)(dst + off) = r;
}

// ---------------- Fused single-pass MoE: x read ONCE, held in registers --------
// Block = 16 tokens, 8 waves. Wave wv owns column/K-slice [wv*256, wv*256+256).
// Phase A: lane (quad,m) streams x[t0+m][slice] fp32->bf16 into 8 bf16x8 regs,
//          MFMA partial logits into lgs[wv] (split-K x8, as in round-3 router).
// Phase B: barrier; wave wv does softmax+top-8 for tokens 2wv,2wv+1 -> LDS meta.
// Phase C: lane already holds x for exactly the output cols it owns:
//          out[m][c] = bf2f(x)*sumw + sum_k w_k * Bb[e_k][c]; Bb is L2-resident.
// LDS: 33.3 KB partials + 832 B meta -> 2 blocks/CU at VGPR<=128.
__global__ __launch_bounds__(512, 4) void moe_fused(
    const float* __restrict__ x, const unsigned short* __restrict__ Wb,
    const float* __restrict__ rb, const unsigned short* __restrict__ Bb,
    float* __restrict__ out) {
  __shared__ float lgs[8][16][E + 1];   // 33.3 KB split-K logit partials
  __shared__ float msw[16];
  __shared__ float mwS[16][TOPK];
  __shared__ int   miS[16][TOPK];       // element offsets e*H

  const int tid = threadIdx.x;
  const int wv = tid >> 6, lane = tid & 63, quad = lane >> 4, m = lane & 15;
  const int t0 = blockIdx.x * 16;
  const int k0 = wv * (H / 8);          // 256-element slice per wave

  // ---- Phase A: stream x (once!) + MFMA partial logits ----
  bf16x8 xa[8];                         // lane's x slice, kept for phase C (32 VGPR)
  f32x4 acc0 = {0.f,0.f,0.f,0.f}, acc1 = {0.f,0.f,0.f,0.f};
  f32x4 acc2 = {0.f,0.f,0.f,0.f}, acc3 = {0.f,0.f,0.f,0.f};
  // A-fragment: lane (quad,m) holds x[t0+m][k0 + it*32 + quad*8 .. +8)
  const float* xp = x + (size_t)(t0 + m) * H + k0 + quad * 8;
  const unsigned short* wp = Wb + (size_t)m * H + k0 + quad * 8;
#pragma unroll
  for (int it = 0; it < 8; ++it) {
    float4 p = *(const float4*)(xp + it * 32);
    float4 q = *(const float4*)(xp + it * 32 + 4);
    bf16x8 av;
    av[0] = (short)f2bf(p.x); av[1] = (short)f2bf(p.y);
    av[2] = (short)f2bf(p.z); av[3] = (short)f2bf(p.w);
    av[4] = (short)f2bf(q.x); av[5] = (short)f2bf(q.y);
    av[6] = (short)f2bf(q.z); av[7] = (short)f2bf(q.w);
    xa[it] = av;
    bf16x8 b0 = *(const bf16x8*)(wp + (size_t)0 * 16 * H + it * 32);
    bf16x8 b1 = *(const bf16x8*)(wp + (size_t)1 * 16 * H + it * 32);
    bf16x8 b2 = *(const bf16x8*)(wp + (size_t)2 * 16 * H + it * 32);
    bf16x8 b3 = *(const bf16x8*)(wp + (size_t)3 * 16 * H + it * 32);
    acc0 = __builtin_amdgcn_mfma_f32_16x16x32_bf16(av, b0, acc0, 0, 0, 0);
    acc1 = __builtin_amdgcn_mfma_f32_16x16x32_bf16(av, b1, acc1, 0, 0, 0);
    acc2 = __builtin_amdgcn_mfma_f32_16x16x32_bf16(av, b2, acc2, 0, 0, 0);
    acc3 = __builtin_amdgcn_mfma_f32_16x16x32_bf16(av, b3, acc3, 0, 0, 0);
  }
  // C/D layout (verified): col = lane&15 (expert-in-group), row = quad*4+r (token)
#pragma unroll
  for (int r = 0; r < 4; ++r) {
    const int row = quad * 4 + r;
    lgs[wv][row][ 0 + m] = acc0[r];
    lgs[wv][row][16 + m] = acc1[r];
    lgs[wv][row][32 + m] = acc2[r];
    lgs[wv][row][48 + m] = acc3[r];
  }
  __syncthreads();

  // ---- Phase B: softmax + top-8; wave wv handles tokens 2wv, 2wv+1 ----
  {
    const float rbl = rb[lane];
#pragma unroll
    for (int tt = 0; tt < 2; ++tt) {
      const int t = wv * 2 + tt;
      float l = rbl;
#pragma unroll
      for (int kq = 0; kq < 8; ++kq) l += lgs[kq][t][lane];
      const float mx = wred_max(l);
      const float p = expf(l - mx);
      const float inv = 1.f / wred_sum(p);
      float sumw = 0.f, lsel = l;
      float mywk = 0.f;
      int myoff = 0;
#pragma unroll
      for (int k = 0; k < TOPK; ++k) {
        const float mk = wred_max(lsel);
        const unsigned long long b = __ballot(lsel == mk);
        const int idx = __ffsll(b) - 1;        // tie -> lowest index (matches top_k)
        const float wk = expf(mk - mx) * inv;
        sumw += wk;
        if (lane == k) { mywk = wk; myoff = idx * H; }
        if (lane == idx) lsel = -FLT_MAX;
      }
      if (lane == 0) msw[t] = sumw;
      if (lane < TOPK) {
        mwS[t][lane] = mywk;
        miS[t][lane] = myoff;
      }
    }
  }
  __syncthreads();

  // ---- Phase C: combine from registers; Bb gathers hit L2 ----
  {
    const float sw = msw[m];
    float wks[TOPK];
    int   ofs[TOPK];
#pragma unroll
    for (int k = 0; k < TOPK; ++k) { wks[k] = mwS[m][k]; ofs[k] = miS[m][k]; }
    float* op = out + (size_t)(t0 + m) * H + k0 + quad * 8;
    const unsigned short* bb = Bb + k0 + quad * 8;
#pragma unroll
    for (int it = 0; it < 8; ++it) {
      const bf16x8 xv = xa[it];
      float o[8];
#pragma unroll
      for (int i = 0; i < 8; ++i) o[i] = bf2f((unsigned short)xv[i]) * sw;
#pragma unroll
      for (int k = 0; k < TOPK; ++k) {
        const bf16x8 bv = *(const bf16x8*)(bb + ofs[k] + it * 32);
        const float wk = wks[k];
#pragma unroll
        for (int i = 0; i < 8; ++i) o[i] += wk * bf2f((unsigned short)bv[i]);
      }
      *(float4*)(op + it * 32)     = make_float4(o[0], o[1], o[2], o[3]);
      *(float4*)(op + it * 32 + 4) = make_float4(o[4], o[5], o[6], o[7]);
    }
  }
}

// ---------------- Fallback fused kernel (no-workspace path) ----------------
template <bool USE_WS>
__global__ __launch_bounds__(NT, 8) void moe_kernel(
    const float* __restrict__ x, const float* __restrict__ W,
    const float* __restrict__ rb, const float* __restrict__ eb,
    const unsigned short* __restrict__ Wb, const unsigned short* __restrict__ Bb,
    float* __restrict__ out) {
  __shared__ unsigned short xl[TT][H + 8];
  __shared__ float lgp[2][TT][E + 1];
  __shared__ float msw[TT];
  __shared__ float mw[TT][TOPK];
  __shared__ int   mi[TT][TOPK];

  const int tid = threadIdx.x;
  const int t0  = blockIdx.x * TT;
  const int wv = tid >> 6, lane = tid & 63, quad = lane >> 4, m = lane & 15;

  {
    const float* row = x + (size_t)(t0 + wv) * H;
#pragma unroll
    for (int i = 0; i < 8; ++i) {
      const int c = (i * 64 + lane) * 4;
      float4 a = *(const float4*)(row + c);
      us4 ra;
      ra[0] = f2bf(a.x); ra[1] = f2bf(a.y); ra[2] = f2bf(a.z); ra[3] = f2bf(a.w);
      *(us4*)&xl[wv][c] = ra;
    }
  }
  __syncthreads();

  {
    const int eg = wv & 3, kh = wv >> 2;
    const int e = eg * 16 + m;
    const int k0 = kh * (H / 2);
    f32x4 acc = {0.f, 0.f, 0.f, 0.f};
    const unsigned short* xp = &xl[m & 7][k0 + quad * 8];
    if (USE_WS) {
      const unsigned short* wp = Wb + (size_t)e * H + k0 + quad * 8;
#pragma unroll 8
      for (int it = 0; it < H / 64; ++it) {
        bf16x8 av = *(const bf16x8*)(xp + it * 32);
        bf16x8 bv = *(const bf16x8*)(wp + it * 32);
        acc = __builtin_amdgcn_mfma_f32_16x16x32_bf16(av, bv, acc, 0, 0, 0);
      }
    } else {
      const float* wp = W + (size_t)e * H + k0 + quad * 8;
#pragma unroll 4
      for (int it = 0; it < H / 64; ++it) {
        bf16x8 av = *(const bf16x8*)(xp + it * 32);
        float4 p = *(const float4*)(wp + it * 32);
        float4 q = *(const float4*)(wp + it * 32 + 4);
        bf16x8 bv;
        bv[0] = (short)f2bf(p.x); bv[1] = (short)f2bf(p.y);
        bv[2] = (short)f2bf(p.z); bv[3] = (short)f2bf(p.w);
        bv[4] = (short)f2bf(q.x); bv[5] = (short)f2bf(q.y);
        bv[6] = (short)f2bf(q.z); bv[7] = (short)f2bf(q.w);
        acc = __builtin_amdgcn_mfma_f32_16x16x32_bf16(av, bv, acc, 0, 0, 0);
      }
    }
#pragma unroll
    for (int r = 0; r < 4; ++r) {
      const int row = quad * 4 + r;
      if (row < TT) lgp[kh][row][eg * 16 + m] = acc[r];
    }
  }
  __syncthreads();

  {
    const int t = wv;
    float l = lgp[0][t][lane] + lgp[1][t][lane] + rb[lane];
    const float mx = wred_max(l);
    const float p = expf(l - mx);
    const float inv = 1.f / wred_sum(p);
    float sumw = 0.f;
    float lsel = l;
#pragma unroll
    for (int k = 0; k < TOPK; ++k) {
      const float mk = wred_max(lsel);
      const unsigned long long b = __ballot(lsel == mk);
      const int idx = __ffsll(b) - 1;
      const float wk = expf(mk - mx) * inv;
      sumw += wk;
      if (lane == 0) { mw[t][k] = wk; mi[t][k] = idx * H; }
      if (lane == idx) lsel = -FLT_MAX;
    }
    if (lane == 0) msw[t] = sumw;
  }
  __syncthreads();

  {
    const int tg = tid >> 8;
    const int c8 = (tid & 255) * 8;
    const unsigned short* bbase = Bb + c8;
    const float* ebase = eb + c8;
#pragma unroll 1
    for (int tt = 0; tt < TT / 2; ++tt) {
      const int t = tg * (TT / 2) + tt;
      const float sw = msw[t];
      const float4 w0 = *(const float4*)&mw[t][0];
      const float4 w1 = *(const float4*)&mw[t][4];
      const int4  e0 = *(const int4*)&mi[t][0];
      const int4  e1 = *(const int4*)&mi[t][4];
      const float wks[8] = {w0.x, w0.y, w0.z, w0.w, w1.x, w1.y, w1.z, w1.w};
      const int   ofs[8] = {e0.x, e0.y, e0.z, e0.w, e1.x, e1.y, e1.z, e1.w};
      bf16x8 xv = *(const bf16x8*)&xl[t][c8];
      float o[8];
#pragma unroll
      for (int i = 0; i < 8; ++i) o[i] = bf2f((unsigned short)xv[i]) * sw;
#pragma unroll
      for (int k = 0; k < TOPK; ++k) {
        const float wk = wks[k];
        if (USE_WS) {
          bf16x8 bv = *(const bf16x8*)(bbase + ofs[k]);
#pragma unroll
          for (int i = 0; i < 8; ++i) o[i] += wk * bf2f((unsigned short)bv[i]);
        } else {
          const float* p = ebase + ofs[k];
          float4 p0 = *(const float4*)p;
          float4 p1 = *(const float4*)(p + 4);
          o[0] += wk * p0.x; o[1] += wk * p0.y; o[2] += wk * p0.z; o[3] += wk * p0.w;
          o[4] += wk * p1.x; o[5] += wk * p1.y; o[6] += wk * p1.z; o[7] += wk * p1.w;
        }
      }
      float* op = out + (size_t)(t0 + t) * H + c8;
      *(float4*)op       = make_float4(o[0], o[1], o[2], o[3]);
      *(float4*)(op + 4) = make_float4(o[4], o[5], o[6], o[7]);
    }
  }
}

extern "C" void kernel_launch(void* const* d_in, const int* in_sizes, int n_in,
                              void* d_out, int out_size, void* d_ws, size_t ws_size,
                              hipStream_t stream) {
  const float* x  = (const float*)d_in[0];
  const float* W  = (const float*)d_in[1];
  const float* rb = (const float*)d_in[2];
  const float* eb = (const float*)d_in[3];
  float* out = (float*)d_out;

  const int T = in_sizes[0] / H;     // 16384
  const size_t szW = (size_t)E * H * sizeof(unsigned short);  // 256 KB
  const size_t need = 2 * szW;                                // 512 KB

  if (ws_size >= need) {
    unsigned short* Wb = (unsigned short*)d_ws;
    unsigned short* Bb = Wb + (size_t)E * H;
    cvt_kernel<<<(2 * E * H) / (256 * 4), 256, 0, stream>>>(W, eb, Wb, Bb);
    moe_fused<<<T / 16, 512, 0, stream>>>(x, Wb, rb, Bb, out);
  } else {
    moe_kernel<false><<<T / TT, NT, 0, stream>>>(x, W, rb, eb, nullptr, nullptr, out);
  }
}

// Round 5
// 306.714 us; speedup vs baseline: 1.0036x; 1.0036x over previous
//
#include <hip/hip_runtime.h>
#include <hip/hip_bf16.h>
#include <float.h>

#define H 2048
#define E 64
#define TOPK 8
#define TT 8     // tokens per block (fallback fused kernel)
#define NT 512   // threads per block (fallback fused kernel)

typedef __attribute__((ext_vector_type(8))) short bf16x8;
typedef __attribute__((ext_vector_type(4))) float f32x4;
typedef __attribute__((ext_vector_type(4))) unsigned short us4;

__device__ __forceinline__ unsigned short f2bf(float f) {
  unsigned u = __float_as_uint(f);
  u += 0x7fffu + ((u >> 16) & 1u);   // RNE
  return (unsigned short)(u >> 16);
}
__device__ __forceinline__ float bf2f(unsigned short s) {
  return __uint_as_float(((unsigned)s) << 16);
}
__device__ __forceinline__ float wred_max(float v) {
#pragma unroll
  for (int o = 32; o > 0; o >>= 1) v = fmaxf(v, __shfl_xor(v, o));
  return v;
}
__device__ __forceinline__ float wred_sum(float v) {
#pragma unroll
  for (int o = 32; o > 0; o >>= 1) v += __shfl_xor(v, o);
  return v;
}

// Convert router_weight and expert_bias fp32 -> bf16 into workspace (L2-resident).
__global__ __launch_bounds__(256) void cvt_kernel(const float* __restrict__ W,
                                                  const float* __restrict__ eb,
                                                  unsigned short* __restrict__ Wb,
                                                  unsigned short* __restrict__ Bb) {
  int i = (blockIdx.x * 256 + threadIdx.x) * 4;
  const float* src;
  unsigned short* dst;
  int off;
  if (i < E * H) { src = W; dst = Wb; off = i; }
  else           { src = eb; dst = Bb; off = i - E * H; }
  float4 v = *(const float4*)(src + off);
  us4 r;
  r[0] = f2bf(v.x); r[1] = f2bf(v.y); r[2] = f2bf(v.z); r[3] = f2bf(v.w);
  *(us4*)(dst + off) = r;
}

// ---------------- Fused single-pass MoE, ILP-batched ----------------
// Block = 16 tokens, 8 waves; wave wv owns K/column slice [wv*256, +256).
// Round-4 post-mortem: VGPR=64 strangled load issue (~2 loads in flight/wave).
// This version explicitly batches: x loads 8-deep, Wb double-buffered 4-deep,
// phase-C gathers 8-deep; __launch_bounds__(512,4) -> 128 VGPR budget.
__global__ __launch_bounds__(512, 4) void moe_fused(
    const float* __restrict__ x, const unsigned short* __restrict__ Wb,
    const float* __restrict__ rb, const unsigned short* __restrict__ Bb,
    float* __restrict__ out) {
  __shared__ float lgs[8][16][E + 1];   // 33.3 KB split-K logit partials
  __shared__ float msw[16];
  __shared__ float mwS[16][TOPK];
  __shared__ int   miS[16][TOPK];       // element offsets e*H

  const int tid = threadIdx.x;
  const int wv = tid >> 6, lane = tid & 63, quad = lane >> 4, m = lane & 15;
  const int t0 = blockIdx.x * 16;
  const int k0 = wv * (H / 8);          // 256-element slice per wave

  // ---- Phase A1: stream x once, batched 8 loads deep; convert to bf16 regs ----
  bf16x8 xa[8];                         // lane's x slice, kept for phase C (32 VGPR)
  const float* xp = x + (size_t)(t0 + m) * H + k0 + quad * 8;
#pragma unroll
  for (int h = 0; h < 2; ++h) {
    float4 xf[8];                       // 8 independent dwordx4 in flight
#pragma unroll
    for (int j = 0; j < 4; ++j) {
      xf[2 * j]     = *(const float4*)(xp + (h * 4 + j) * 32);
      xf[2 * j + 1] = *(const float4*)(xp + (h * 4 + j) * 32 + 4);
    }
#pragma unroll
    for (int j = 0; j < 4; ++j) {
      const float4 p = xf[2 * j], q = xf[2 * j + 1];
      bf16x8 av;
      av[0] = (short)f2bf(p.x); av[1] = (short)f2bf(p.y);
      av[2] = (short)f2bf(p.z); av[3] = (short)f2bf(p.w);
      av[4] = (short)f2bf(q.x); av[5] = (short)f2bf(q.y);
      av[6] = (short)f2bf(q.z); av[7] = (short)f2bf(q.w);
      xa[h * 4 + j] = av;
    }
  }

  // ---- Phase A2: MFMA partial logits; Wb double-buffered in registers ----
  f32x4 acc0 = {0.f,0.f,0.f,0.f}, acc1 = {0.f,0.f,0.f,0.f};
  f32x4 acc2 = {0.f,0.f,0.f,0.f}, acc3 = {0.f,0.f,0.f,0.f};
  const unsigned short* wp = Wb + (size_t)m * H + k0 + quad * 8;
  bf16x8 wbuf[2][4];                    // all indices compile-time after unroll
#pragma unroll
  for (int g = 0; g < 4; ++g)
    wbuf[0][g] = *(const bf16x8*)(wp + (size_t)g * 16 * H);
#pragma unroll
  for (int it = 0; it < 8; ++it) {
    const int cur = it & 1, nxt = cur ^ 1;
    if (it < 7) {
#pragma unroll
      for (int g = 0; g < 4; ++g)
        wbuf[nxt][g] = *(const bf16x8*)(wp + (size_t)g * 16 * H + (it + 1) * 32);
    }
    acc0 = __builtin_amdgcn_mfma_f32_16x16x32_bf16(xa[it], wbuf[cur][0], acc0, 0, 0, 0);
    acc1 = __builtin_amdgcn_mfma_f32_16x16x32_bf16(xa[it], wbuf[cur][1], acc1, 0, 0, 0);
    acc2 = __builtin_amdgcn_mfma_f32_16x16x32_bf16(xa[it], wbuf[cur][2], acc2, 0, 0, 0);
    acc3 = __builtin_amdgcn_mfma_f32_16x16x32_bf16(xa[it], wbuf[cur][3], acc3, 0, 0, 0);
  }
  // C/D layout (verified): col = lane&15 (expert-in-group), row = quad*4+r (token)
#pragma unroll
  for (int r = 0; r < 4; ++r) {
    const int row = quad * 4 + r;
    lgs[wv][row][ 0 + m] = acc0[r];
    lgs[wv][row][16 + m] = acc1[r];
    lgs[wv][row][32 + m] = acc2[r];
    lgs[wv][row][48 + m] = acc3[r];
  }
  __syncthreads();

  // ---- Phase B: softmax + top-8; wave wv handles tokens 2wv, 2wv+1 ----
  {
    const float rbl = rb[lane];
#pragma unroll
    for (int tt = 0; tt < 2; ++tt) {
      const int t = wv * 2 + tt;
      float l = rbl;
#pragma unroll
      for (int kq = 0; kq < 8; ++kq) l += lgs[kq][t][lane];
      const float mx = wred_max(l);
      const float p = expf(l - mx);
      const float inv = 1.f / wred_sum(p);
      float sumw = 0.f, lsel = l;
      float mywk = 0.f;
      int myoff = 0;
#pragma unroll
      for (int k = 0; k < TOPK; ++k) {
        const float mk = wred_max(lsel);
        const unsigned long long b = __ballot(lsel == mk);
        const int idx = __ffsll(b) - 1;        // tie -> lowest index (matches top_k)
        const float wk = expf(mk - mx) * inv;
        sumw += wk;
        if (lane == k) { mywk = wk; myoff = idx * H; }
        if (lane == idx) lsel = -FLT_MAX;
      }
      if (lane == 0) msw[t] = sumw;
      if (lane < TOPK) {
        mwS[t][lane] = mywk;
        miS[t][lane] = myoff;
      }
    }
  }
  __syncthreads();

  // ---- Phase C: combine from registers; batched 8-deep L2 gathers of Bb ----
  {
    const float sw = msw[m];
    const float4 w0 = *(const float4*)&mwS[m][0];
    const float4 w1 = *(const float4*)&mwS[m][4];
    const int4  e0 = *(const int4*)&miS[m][0];
    const int4  e1 = *(const int4*)&miS[m][4];
    const float wks[8] = {w0.x, w0.y, w0.z, w0.w, w1.x, w1.y, w1.z, w1.w};
    const int   ofs[8] = {e0.x, e0.y, e0.z, e0.w, e1.x, e1.y, e1.z, e1.w};
    float* op = out + (size_t)(t0 + m) * H + k0 + quad * 8;
    const unsigned short* bb = Bb + k0 + quad * 8;
#pragma unroll
    for (int it = 0; it < 8; ++it) {
      bf16x8 bv[8];                     // all 8 gathers issued before use
#pragma unroll
      for (int k = 0; k < TOPK; ++k)
        bv[k] = *(const bf16x8*)(bb + ofs[k] + it * 32);
      const bf16x8 xv = xa[it];
      float o[8];
#pragma unroll
      for (int i = 0; i < 8; ++i) o[i] = bf2f((unsigned short)xv[i]) * sw;
#pragma unroll
      for (int k = 0; k < TOPK; ++k) {
        const float wk = wks[k];
#pragma unroll
        for (int i = 0; i < 8; ++i) o[i] += wk * bf2f((unsigned short)bv[k][i]);
      }
      *(float4*)(op + it * 32)     = make_float4(o[0], o[1], o[2], o[3]);
      *(float4*)(op + it * 32 + 4) = make_float4(o[4], o[5], o[6], o[7]);
    }
  }
}

// ---------------- Fallback fused kernel (no-workspace path) ----------------
template <bool USE_WS>
__global__ __launch_bounds__(NT, 8) void moe_kernel(
    const float* __restrict__ x, const float* __restrict__ W,
    const float* __restrict__ rb, const float* __restrict__ eb,
    const unsigned short* __restrict__ Wb, const unsigned short* __restrict__ Bb,
    float* __restrict__ out) {
  __shared__ unsigned short xl[TT][H + 8];
  __shared__ float lgp[2][TT][E + 1];
  __shared__ float msw[TT];
  __shared__ float mw[TT][TOPK];
  __shared__ int   mi[TT][TOPK];

  const int tid = threadIdx.x;
  const int t0  = blockIdx.x * TT;
  const int wv = tid >> 6, lane = tid & 63, quad = lane >> 4, m = lane & 15;

  {
    const float* row = x + (size_t)(t0 + wv) * H;
#pragma unroll
    for (int i = 0; i < 8; ++i) {
      const int c = (i * 64 + lane) * 4;
      float4 a = *(const float4*)(row + c);
      us4 ra;
      ra[0] = f2bf(a.x); ra[1] = f2bf(a.y); ra[2] = f2bf(a.z); ra[3] = f2bf(a.w);
      *(us4*)&xl[wv][c] = ra;
    }
  }
  __syncthreads();

  {
    const int eg = wv & 3, kh = wv >> 2;
    const int e = eg * 16 + m;
    const int k0 = kh * (H / 2);
    f32x4 acc = {0.f, 0.f, 0.f, 0.f};
    const unsigned short* xp = &xl[m & 7][k0 + quad * 8];
    if (USE_WS) {
      const unsigned short* wp = Wb + (size_t)e * H + k0 + quad * 8;
#pragma unroll 8
      for (int it = 0; it < H / 64; ++it) {
        bf16x8 av = *(const bf16x8*)(xp + it * 32);
        bf16x8 bv = *(const bf16x8*)(wp + it * 32);
        acc = __builtin_amdgcn_mfma_f32_16x16x32_bf16(av, bv, acc, 0, 0, 0);
      }
    } else {
      const float* wp = W + (size_t)e * H + k0 + quad * 8;
#pragma unroll 4
      for (int it = 0; it < H / 64; ++it) {
        bf16x8 av = *(const bf16x8*)(xp + it * 32);
        float4 p = *(const float4*)(wp + it * 32);
        float4 q = *(const float4*)(wp + it * 32 + 4);
        bf16x8 bv;
        bv[0] = (short)f2bf(p.x); bv[1] = (short)f2bf(p.y);
        bv[2] = (short)f2bf(p.z); bv[3] = (short)f2bf(p.w);
        bv[4] = (short)f2bf(q.x); bv[5] = (short)f2bf(q.y);
        bv[6] = (short)f2bf(q.z); bv[7] = (short)f2bf(q.w);
        acc = __builtin_amdgcn_mfma_f32_16x16x32_bf16(av, bv, acc, 0, 0, 0);
      }
    }
#pragma unroll
    for (int r = 0; r < 4; ++r) {
      const int row = quad * 4 + r;
      if (row < TT) lgp[kh][row][eg * 16 + m] = acc[r];
    }
  }
  __syncthreads();

  {
    const int t = wv;
    float l = lgp[0][t][lane] + lgp[1][t][lane] + rb[lane];
    const float mx = wred_max(l);
    const float p = expf(l - mx);
    const float inv = 1.f / wred_sum(p);
    float sumw = 0.f;
    float lsel = l;
#pragma unroll
    for (int k = 0; k < TOPK; ++k) {
      const float mk = wred_max(lsel);
      const unsigned long long b = __ballot(lsel == mk);
      const int idx = __ffsll(b) - 1;
      const float wk = expf(mk - mx) * inv;
      sumw += wk;
      if (lane == 0) { mw[t][k] = wk; mi[t][k] = idx * H; }
      if (lane == idx) lsel = -FLT_MAX;
    }
    if (lane == 0) msw[t] = sumw;
  }
  __syncthreads();

  {
    const int tg = tid >> 8;
    const int c8 = (tid & 255) * 8;
    const unsigned short* bbase = Bb + c8;
    const float* ebase = eb + c8;
#pragma unroll 1
    for (int tt = 0; tt < TT / 2; ++tt) {
      const int t = tg * (TT / 2) + tt;
      const float sw = msw[t];
      const float4 w0 = *(const float4*)&mw[t][0];
      const float4 w1 = *(const float4*)&mw[t][4];
      const int4  e0 = *(const int4*)&mi[t][0];
      const int4  e1 = *(const int4*)&mi[t][4];
      const float wks[8] = {w0.x, w0.y, w0.z, w0.w, w1.x, w1.y, w1.z, w1.w};
      const int   ofs[8] = {e0.x, e0.y, e0.z, e0.w, e1.x, e1.y, e1.z, e1.w};
      bf16x8 xv = *(const bf16x8*)&xl[t][c8];
      float o[8];
#pragma unroll
      for (int i = 0; i < 8; ++i) o[i] = bf2f((unsigned short)xv[i]) * sw;
#pragma unroll
      for (int k = 0; k < TOPK; ++k) {
        const float wk = wks[k];
        if (USE_WS) {
          bf16x8 bv = *(const bf16x8*)(bbase + ofs[k]);
#pragma unroll
          for (int i = 0; i < 8; ++i) o[i] += wk * bf2f((unsigned short)bv[i]);
        } else {
          const float* p = ebase + ofs[k];
          float4 p0 = *(const float4*)p;
          float4 p1 = *(const float4*)(p + 4);
          o[0] += wk * p0.x; o[1] += wk * p0.y; o[2] += wk * p0.z; o[3] += wk * p0.w;
          o[4] += wk * p1.x; o[5] += wk * p1.y; o[6] += wk * p1.z; o[7] += wk * p1.w;
        }
      }
      float* op = out + (size_t)(t0 + t) * H + c8;
      *(float4*)op       = make_float4(o[0], o[1], o[2], o[3]);
      *(float4*)(op + 4) = make_float4(o[4], o[5], o[6], o[7]);
    }
  }
}

extern "C" void kernel_launch(void* const* d_in, const int* in_sizes, int n_in,
                              void* d_out, int out_size, void* d_ws, size_t ws_size,
                              hipStream_t stream) {
  const float* x  = (const float*)d_in[0];
  const float* W  = (const float*)d_in[1];
  const float* rb = (const float*)d_in[2];
  const float* eb = (const float*)d_in[3];
  float* out = (float*)d_out;

  const int T = in_sizes[0] / H;     // 16384
  const size_t szW = (size_t)E * H * sizeof(unsigned short);  // 256 KB
  const size_t need = 2 * szW;                                // 512 KB

  if (ws_size >= need) {
    unsigned short* Wb = (unsigned short*)d_ws;
    unsigned short* Bb = Wb + (size_t)E * H;
    cvt_kernel<<<(2 * E * H) / (256 * 4), 256, 0, stream>>>(W, eb, Wb, Bb);
    moe_fused<<<T / 16, 512, 0, stream>>>(x, Wb, rb, Bb, out);
  } else {
    moe_kernel<false><<<T / TT, NT, 0, stream>>>(x, W, rb, eb, nullptr, nullptr, out);
  }
}

// Round 6
// 280.399 us; speedup vs baseline: 1.0978x; 1.0939x over previous
//
#include <hip/hip_runtime.h>
#include <hip/hip_bf16.h>
#include <float.h>

#define H 2048
#define E 64
#define TOPK 8
#define RTT 32   // tokens per router block
#define NCH 32   // K chunks of 64 columns each
#define TT 8     // tokens per block (fallback fused kernel)
#define NT 512   // threads per block (fallback fused kernel)

typedef __attribute__((ext_vector_type(8))) short bf16x8;
typedef __attribute__((ext_vector_type(4))) float f32x4;
typedef __attribute__((ext_vector_type(4))) unsigned short us4;

__device__ __forceinline__ unsigned short f2bf(float f) {
  unsigned u = __float_as_uint(f);
  u += 0x7fffu + ((u >> 16) & 1u);   // RNE
  return (unsigned short)(u >> 16);
}
__device__ __forceinline__ float bf2f(unsigned short s) {
  return __uint_as_float(((unsigned)s) << 16);
}
__device__ __forceinline__ float wred_max(float v) {
#pragma unroll
  for (int o = 32; o > 0; o >>= 1) v = fmaxf(v, __shfl_xor(v, o));
  return v;
}
__device__ __forceinline__ float wred_sum(float v) {
#pragma unroll
  for (int o = 32; o > 0; o >>= 1) v += __shfl_xor(v, o);
  return v;
}

// Direct-to-LDS DMA: 16 B per lane, dest = wave-uniform base + lane*16.
__device__ __forceinline__ void gll16(const float* g, const float* l) {
  __builtin_amdgcn_global_load_lds(
      (const __attribute__((address_space(1))) void*)g,
      (__attribute__((address_space(3))) void*)l, 16, 0, 0);
}

// Convert router_weight and expert_bias fp32 -> bf16 into workspace (L2-resident).
__global__ __launch_bounds__(256) void cvt_kernel(const float* __restrict__ W,
                                                  const float* __restrict__ eb,
                                                  unsigned short* __restrict__ Wb,
                                                  unsigned short* __restrict__ Bb) {
  int i = (blockIdx.x * 256 + threadIdx.x) * 4;
  const float* src;
  unsigned short* dst;
  int off;
  if (i < E * H) { src = W; dst = Wb; off = i; }
  else           { src = eb; dst = Bb; off = i - E * H; }
  float4 v = *(const float4*)(src + off);
  us4 r;
  r[0] = f2bf(v.x); r[1] = f2bf(v.y); r[2] = f2bf(v.z); r[3] = f2bf(v.w);
  *(us4*)(dst + off) = r;
}

// ---------------- Router: gll-pipelined x stream + full-K per-wave MFMA -------
// Block = 32 tokens, 8 waves. Wave wv = (tg = wv&1 token-half, eg = wv>>1
// expert-group): accumulates logits[16 tok x 16 exp] over FULL K in one f32x4
// (no split-K reduction). x staged fp32 via global_load_lds into a 4-deep
// 8 KB chunk ring; counted vmcnt(2) keeps 2 chunks in flight ACROSS the raw
// s_barrier (T3/T4). LDS rows are 256 B -> XOR-swizzle byte^((row&7)<<4),
// applied both-sides: linear gll dest + inverse-swizzled GLOBAL source col +
// swizzled read (rule 21).
__global__ __launch_bounds__(512, 4) void router_kernel(
    const float* __restrict__ x, const unsigned short* __restrict__ Wb,
    const float* __restrict__ rb, float* __restrict__ msw_g,
    float* __restrict__ mw_g, int* __restrict__ mi_g) {
  __shared__ float xch[4][RTT][64];   // 32 KB chunk ring (chunk = 32 tok x 64 col)
  __shared__ float lgs[RTT][E + 1];   // 8.3 KB final logits

  const int tid = threadIdx.x;
  const int wv = tid >> 6, lane = tid & 63, quad = lane >> 4, m = lane & 15;
  const int t0 = blockIdx.x * RTT;
  const int tg = wv & 1, eg = wv >> 1;

  // Staging: wave wv fills rows 4wv..4wv+3 (1 KB) of each chunk; lane ->
  // (row sr, 16B-slot sj). Source col inverse-swizzled so linear LDS holds
  // swizzled data.
  const int sr = 4 * wv + (lane >> 4);
  const int sj = lane & 15;
  const int scol = ((sj * 16) ^ ((sr & 7) << 4)) >> 2;
  const float* sgp = x + (size_t)(t0 + sr) * H + scol;

  f32x4 acc = {0.f, 0.f, 0.f, 0.f};
  const unsigned short* wp = Wb + (size_t)(eg * 16 + m) * H + quad * 8;

  // prologue: chunks 0 and 1 in flight
  gll16(sgp + 0 * 64, &xch[0][4 * wv][0]);
  gll16(sgp + 1 * 64, &xch[1][4 * wv][0]);

  const int rbase = tg * 16 + m;          // A-row (token) this lane reads
  const int swz = (rbase & 7) << 4;       // read-side XOR

#pragma unroll 1
  for (int c = 0; c < NCH; ++c) {
    if (c + 2 < NCH) {
      gll16(sgp + (c + 2) * 64, &xch[(c + 2) & 3][4 * wv][0]);
      // outstanding: gll(c+1), gll(c+2) -> wait gll(c) landed in LDS
      asm volatile("s_waitcnt vmcnt(2)" ::: "memory");
    } else {
      asm volatile("s_waitcnt vmcnt(0)" ::: "memory");
    }
    __builtin_amdgcn_s_barrier();
    // single barrier/iter is safe: buf[(c+2)&3] was read at iter c-2, and
    // every wave passed barrier(c-1) after finishing process(c-2).
    const char* cb = (const char*)&xch[c & 3][0][0] + rbase * 256;
#pragma unroll
    for (int ks = 0; ks < 2; ++ks) {
      const int b = ks * 128 + quad * 32;
      const float4 f0 = *(const float4*)(cb + ((b +  0) ^ swz));
      const float4 f1 = *(const float4*)(cb + ((b + 16) ^ swz));
      bf16x8 av;
      av[0] = (short)f2bf(f0.x); av[1] = (short)f2bf(f0.y);
      av[2] = (short)f2bf(f0.z); av[3] = (short)f2bf(f0.w);
      av[4] = (short)f2bf(f1.x); av[5] = (short)f2bf(f1.y);
      av[6] = (short)f2bf(f1.z); av[7] = (short)f2bf(f1.w);
      const bf16x8 bv = *(const bf16x8*)(wp + c * 64 + ks * 32);
      acc = __builtin_amdgcn_mfma_f32_16x16x32_bf16(av, bv, acc, 0, 0, 0);
    }
  }

  // C/D layout (verified): col = lane&15 (expert-in-group), row = quad*4+r (token)
#pragma unroll
  for (int r = 0; r < 4; ++r)
    lgs[tg * 16 + quad * 4 + r][eg * 16 + m] = acc[r];
  __syncthreads();

  // Softmax + top-8: wave wv handles tokens 4wv..4wv+3; lane = expert.
  const float rbl = rb[lane];
#pragma unroll
  for (int tt = 0; tt < 4; ++tt) {
    const int t = wv * 4 + tt;
    float l = lgs[t][lane] + rbl;
    const float mx = wred_max(l);
    const float p = expf(l - mx);
    const float inv = 1.f / wred_sum(p);
    float sumw = 0.f, lsel = l;
    float mywk = 0.f;
    int myoff = 0;
#pragma unroll
    for (int k = 0; k < TOPK; ++k) {
      const float mk = wred_max(lsel);
      const unsigned long long bmask = __ballot(lsel == mk);
      const int idx = __ffsll(bmask) - 1;      // tie -> lowest index (matches top_k)
      const float wk = expf(mk - mx) * inv;
      sumw += wk;
      if (lane == k) { mywk = wk; myoff = idx * H; }
      if (lane == idx) lsel = -FLT_MAX;
    }
    const int tgl = t0 + t;
    if (lane == 0) msw_g[tgl] = sumw;
    if (lane < TOPK) {
      mw_g[(size_t)tgl * TOPK + lane] = mywk;
      mi_g[(size_t)tgl * TOPK + lane] = myoff;
    }
  }
}

// ---------------- Combine: barrier-free, LDS-free pure streaming ----------------
// One wave per token. out[t] = x_fp32[t]*sumw + sum_k w_k * Bb[off_k].
__global__ __launch_bounds__(256, 4) void combine_kernel(
    const float* __restrict__ x, const unsigned short* __restrict__ Bb,
    const float* __restrict__ msw_g, const float* __restrict__ mw_g,
    const int* __restrict__ mi_g, float* __restrict__ out) {
  const int tid = threadIdx.x;
  const int wv = tid >> 6, lane = tid & 63;
  const int t = blockIdx.x * 4 + wv;
  const float sw = msw_g[t];
  const float4 w0 = *(const float4*)(mw_g + (size_t)t * TOPK);
  const float4 w1 = *(const float4*)(mw_g + (size_t)t * TOPK + 4);
  const int4  e0 = *(const int4*)(mi_g + (size_t)t * TOPK);
  const int4  e1 = *(const int4*)(mi_g + (size_t)t * TOPK + 4);
  const float wks[8] = {w0.x, w0.y, w0.z, w0.w, w1.x, w1.y, w1.z, w1.w};
  const int   ofs[8] = {e0.x, e0.y, e0.z, e0.w, e1.x, e1.y, e1.z, e1.w};
  const float* xr = x + (size_t)t * H;
  float* orow = out + (size_t)t * H;
#pragma unroll
  for (int ch = 0; ch < 4; ++ch) {
    const int c8 = ch * 512 + lane * 8;
    const float4 xa = *(const float4*)(xr + c8);
    const float4 xb = *(const float4*)(xr + c8 + 4);
    float o[8] = {xa.x * sw, xa.y * sw, xa.z * sw, xa.w * sw,
                  xb.x * sw, xb.y * sw, xb.z * sw, xb.w * sw};
#pragma unroll
    for (int k = 0; k < TOPK; ++k) {
      const bf16x8 bv = *(const bf16x8*)(Bb + ofs[k] + c8);
      const float wk = wks[k];
#pragma unroll
      for (int i = 0; i < 8; ++i) o[i] += wk * bf2f((unsigned short)bv[i]);
    }
    *(float4*)(orow + c8)     = make_float4(o[0], o[1], o[2], o[3]);
    *(float4*)(orow + c8 + 4) = make_float4(o[4], o[5], o[6], o[7]);
  }
}

// ---------------- Fallback fused kernel (no-workspace path) ----------------
__global__ __launch_bounds__(NT, 8) void moe_kernel(
    const float* __restrict__ x, const float* __restrict__ W,
    const float* __restrict__ rb, const float* __restrict__ eb,
    float* __restrict__ out) {
  __shared__ unsigned short xl[TT][H + 8];
  __shared__ float lgp[2][TT][E + 1];
  __shared__ float msw[TT];
  __shared__ float mw[TT][TOPK];
  __shared__ int   mi[TT][TOPK];

  const int tid = threadIdx.x;
  const int t0  = blockIdx.x * TT;
  const int wv = tid >> 6, lane = tid & 63, quad = lane >> 4, m = lane & 15;

  {
    const float* row = x + (size_t)(t0 + wv) * H;
#pragma unroll
    for (int i = 0; i < 8; ++i) {
      const int c = (i * 64 + lane) * 4;
      float4 a = *(const float4*)(row + c);
      us4 ra;
      ra[0] = f2bf(a.x); ra[1] = f2bf(a.y); ra[2] = f2bf(a.z); ra[3] = f2bf(a.w);
      *(us4*)&xl[wv][c] = ra;
    }
  }
  __syncthreads();

  {
    const int eg = wv & 3, kh = wv >> 2;
    const int e = eg * 16 + m;
    const int k0 = kh * (H / 2);
    f32x4 acc = {0.f, 0.f, 0.f, 0.f};
    const unsigned short* xp = &xl[m & 7][k0 + quad * 8];
    const float* wpp = W + (size_t)e * H + k0 + quad * 8;
#pragma unroll 4
    for (int it = 0; it < H / 64; ++it) {
      bf16x8 av = *(const bf16x8*)(xp + it * 32);
      float4 p = *(const float4*)(wpp + it * 32);
      float4 q = *(const float4*)(wpp + it * 32 + 4);
      bf16x8 bv;
      bv[0] = (short)f2bf(p.x); bv[1] = (short)f2bf(p.y);
      bv[2] = (short)f2bf(p.z); bv[3] = (short)f2bf(p.w);
      bv[4] = (short)f2bf(q.x); bv[5] = (short)f2bf(q.y);
      bv[6] = (short)f2bf(q.z); bv[7] = (short)f2bf(q.w);
      acc = __builtin_amdgcn_mfma_f32_16x16x32_bf16(av, bv, acc, 0, 0, 0);
    }
#pragma unroll
    for (int r = 0; r < 4; ++r) {
      const int row = quad * 4 + r;
      if (row < TT) lgp[kh][row][eg * 16 + m] = acc[r];
    }
  }
  __syncthreads();

  {
    const int t = wv;
    float l = lgp[0][t][lane] + lgp[1][t][lane] + rb[lane];
    const float mx = wred_max(l);
    const float p = expf(l - mx);
    const float inv = 1.f / wred_sum(p);
    float sumw = 0.f;
    float lsel = l;
#pragma unroll
    for (int k = 0; k < TOPK; ++k) {
      const float mk = wred_max(lsel);
      const unsigned long long b = __ballot(lsel == mk);
      const int idx = __ffsll(b) - 1;
      const float wk = expf(mk - mx) * inv;
      sumw += wk;
      if (lane == 0) { mw[t][k] = wk; mi[t][k] = idx * H; }
      if (lane == idx) lsel = -FLT_MAX;
    }
    if (lane == 0) msw[t] = sumw;
  }
  __syncthreads();

  {
    const int tg = tid >> 8;
    const int c8 = (tid & 255) * 8;
    const float* ebase = eb + c8;
#pragma unroll 1
    for (int tt = 0; tt < TT / 2; ++tt) {
      const int t = tg * (TT / 2) + tt;
      const float sw = msw[t];
      const float4 w0 = *(const float4*)&mw[t][0];
      const float4 w1 = *(const float4*)&mw[t][4];
      const int4  e0 = *(const int4*)&mi[t][0];
      const int4  e1 = *(const int4*)&mi[t][4];
      const float wks[8] = {w0.x, w0.y, w0.z, w0.w, w1.x, w1.y, w1.z, w1.w};
      const int   ofs[8] = {e0.x, e0.y, e0.z, e0.w, e1.x, e1.y, e1.z, e1.w};
      bf16x8 xv = *(const bf16x8*)&xl[t][c8];
      float o[8];
#pragma unroll
      for (int i = 0; i < 8; ++i) o[i] = bf2f((unsigned short)xv[i]) * sw;
#pragma unroll
      for (int k = 0; k < TOPK; ++k) {
        const float wk = wks[k];
        const float* p = ebase + ofs[k];
        float4 p0 = *(const float4*)p;
        float4 p1 = *(const float4*)(p + 4);
        o[0] += wk * p0.x; o[1] += wk * p0.y; o[2] += wk * p0.z; o[3] += wk * p0.w;
        o[4] += wk * p1.x; o[5] += wk * p1.y; o[6] += wk * p1.z; o[7] += wk * p1.w;
      }
      float* op = out + (size_t)(t0 + t) * H + c8;
      *(float4*)op       = make_float4(o[0], o[1], o[2], o[3]);
      *(float4*)(op + 4) = make_float4(o[4], o[5], o[6], o[7]);
    }
  }
}

extern "C" void kernel_launch(void* const* d_in, const int* in_sizes, int n_in,
                              void* d_out, int out_size, void* d_ws, size_t ws_size,
                              hipStream_t stream) {
  const float* x  = (const float*)d_in[0];
  const float* W  = (const float*)d_in[1];
  const float* rb = (const float*)d_in[2];
  const float* eb = (const float*)d_in[3];
  float* out = (float*)d_out;

  const int T = in_sizes[0] / H;     // 16384
  const size_t szW = (size_t)E * H * sizeof(unsigned short);        // 256 KB
  const size_t meta_sz = (size_t)T * 4 + (size_t)T * TOPK * 4 * 2;  // ~1.06 MB
  const size_t need = 2 * szW + meta_sz;

  if (ws_size >= need) {
    unsigned short* Wb = (unsigned short*)d_ws;
    unsigned short* Bb = Wb + (size_t)E * H;
    float* msw_g = (float*)(Bb + (size_t)E * H);
    float* mw_g  = msw_g + T;
    int*   mi_g  = (int*)(mw_g + (size_t)T * TOPK);
    cvt_kernel<<<(2 * E * H) / (256 * 4), 256, 0, stream>>>(W, eb, Wb, Bb);
    router_kernel<<<T / RTT, 512, 0, stream>>>(x, Wb, rb, msw_g, mw_g, mi_g);
    combine_kernel<<<T / 4, 256, 0, stream>>>(x, Bb, msw_g, mw_g, mi_g, out);
  } else {
    moe_kernel<<<T / TT, NT, 0, stream>>>(x, W, rb, eb, out);
  }
}

// Round 7
// 277.636 us; speedup vs baseline: 1.1087x; 1.0100x over previous
//
#include <hip/hip_runtime.h>
#include <hip/hip_bf16.h>
#include <float.h>

#define H 2048
#define E 64
#define TOPK 8
#define RTT 32   // tokens per router block
#define NCH 32   // K chunks of 64 columns each
#define TT 8     // tokens per block (fallback fused kernel)
#define NT 512   // threads per block (fallback fused kernel)

typedef __attribute__((ext_vector_type(8))) short bf16x8;
typedef __attribute__((ext_vector_type(4))) float f32x4;
typedef __attribute__((ext_vector_type(4))) unsigned short us4;

__device__ __forceinline__ unsigned short f2bf(float f) {
  unsigned u = __float_as_uint(f);
  u += 0x7fffu + ((u >> 16) & 1u);   // RNE
  return (unsigned short)(u >> 16);
}
__device__ __forceinline__ float bf2f(unsigned short s) {
  return __uint_as_float(((unsigned)s) << 16);
}
__device__ __forceinline__ float wred_max(float v) {
#pragma unroll
  for (int o = 32; o > 0; o >>= 1) v = fmaxf(v, __shfl_xor(v, o));
  return v;
}
__device__ __forceinline__ float wred_sum(float v) {
#pragma unroll
  for (int o = 32; o > 0; o >>= 1) v += __shfl_xor(v, o);
  return v;
}

// Direct-to-LDS DMA: 16 B per lane, dest = wave-uniform base + lane*16.
__device__ __forceinline__ void gll16(const void* g, const void* l) {
  __builtin_amdgcn_global_load_lds(
      (const __attribute__((address_space(1))) void*)g,
      (__attribute__((address_space(3))) void*)l, 16, 0, 0);
}

// Convert router_weight and expert_bias fp32 -> bf16 into workspace (L2-resident).
__global__ __launch_bounds__(256) void cvt_kernel(const float* __restrict__ W,
                                                  const float* __restrict__ eb,
                                                  unsigned short* __restrict__ Wb,
                                                  unsigned short* __restrict__ Bb) {
  int i = (blockIdx.x * 256 + threadIdx.x) * 4;
  const float* src;
  unsigned short* dst;
  int off;
  if (i < E * H) { src = W; dst = Wb; off = i; }
  else           { src = eb; dst = Bb; off = i - E * H; }
  float4 v = *(const float4*)(src + off);
  us4 r;
  r[0] = f2bf(v.x); r[1] = f2bf(v.y); r[2] = f2bf(v.z); r[3] = f2bf(v.w);
  *(us4*)(dst + off) = r;
}

// ---------------- Router: dual-gll pipelined (x AND Wb through LDS) -----------
// R6 post-mortem: Wb register loads in the K-loop were vmem ops consumed
// immediately -> compiler-inserted vmcnt(<=1) drained the gll queue; pipeline
// was depth-0. Fix: stage the 8 KB Wb chunk via global_load_lds too, so the
// loop's ONLY vmem ops are 2 glls/chunk and my counted vmcnt(4) keeps 2 chunks
// in flight across the raw s_barrier (T3/T4). Both LDS tiles use the verified
// both-sides XOR swizzle (linear gll dest + inverse-swizzled global source +
// swizzled ds_read; rule 21).
__global__ __launch_bounds__(512, 4) void router_kernel(
    const float* __restrict__ x, const unsigned short* __restrict__ Wb,
    const float* __restrict__ rb, float* __restrict__ msw_g,
    float* __restrict__ mw_g, int* __restrict__ mi_g) {
  __shared__ float xch[4][RTT][64];            // 32 KB x ring (32 tok x 64 col)
  __shared__ unsigned short wch[4][E][64];     // 32 KB Wb ring (64 exp x 64 col bf16)
  __shared__ float lgs[RTT][E + 1];            // 8.3 KB final logits

  const int tid = threadIdx.x;
  const int wv = tid >> 6, lane = tid & 63, quad = lane >> 4, m = lane & 15;
  const int t0 = blockIdx.x * RTT;
  const int tg = wv & 1, eg = wv >> 1;

  // --- x staging (verified in R6): wave wv fills rows 4wv..4wv+3 ---
  const int sr = 4 * wv + (lane >> 4);
  const int sj = lane & 15;
  const int scol = ((sj * 16) ^ ((sr & 7) << 4)) >> 2;   // inverse-swz source col
  const float* xsp = x + (size_t)(t0 + sr) * H + scol;

  // --- Wb staging: wave wv fills expert rows 8wv..8wv+7; slot = lane&7 ---
  // LDS row = 128 B; swizzle byte ^ ((e&7)<<4); e&7 == lane>>3 for this wave.
  const int we = wv * 8 + (lane >> 3);
  const int wslot = lane & 7;
  const int wsrc = (wslot ^ (lane >> 3)) * 8;            // inverse-swz source col (shorts)
  const unsigned short* wsp = Wb + (size_t)we * H + wsrc;

  f32x4 acc = {0.f, 0.f, 0.f, 0.f};

  // prologue: chunks 0 and 1 in flight (4 gll ops)
  gll16(xsp + 0 * 64, &xch[0][4 * wv][0]);
  gll16(wsp + 0 * 64, &wch[0][wv * 8][0]);
  gll16(xsp + 1 * 64, &xch[1][4 * wv][0]);
  gll16(wsp + 1 * 64, &wch[1][wv * 8][0]);

  const int rbase = tg * 16 + m;          // A-row (token) this lane reads
  const int swzX = (rbase & 7) << 4;      // x read-side XOR
  const int e = eg * 16 + m;              // B-row (expert) this lane reads
  const int swzW = (m & 7) << 4;          // Wb read-side XOR ((e&7)==(m&7))

#pragma unroll 1
  for (int c = 0; c < NCH; ++c) {
    if (c + 2 < NCH) {
      gll16(xsp + (c + 2) * 64, &xch[(c + 2) & 3][4 * wv][0]);
      gll16(wsp + (c + 2) * 64, &wch[(c + 2) & 3][wv * 8][0]);
      // outstanding: {x,w}(c+1), {x,w}(c+2) stay in flight; {x,w}(c) retired
      asm volatile("s_waitcnt vmcnt(4)" ::: "memory");
    } else if (c + 1 < NCH) {
      asm volatile("s_waitcnt vmcnt(2)" ::: "memory");
    } else {
      asm volatile("s_waitcnt vmcnt(0)" ::: "memory");
    }
    __builtin_amdgcn_s_barrier();
    // WAW safe: gll(c+2) targets buf[(c-2)&3], last read in body(c-2); every
    // wave passed barrier(c-1) only after body(c-2) completed (verified R6).
    const char* cbx = (const char*)&xch[c & 3][0][0] + rbase * 256;
    const char* cbw = (const char*)&wch[c & 3][0][0] + e * 128;
#pragma unroll
    for (int ks = 0; ks < 2; ++ks) {
      const int bx = ks * 128 + quad * 32;
      const float4 f0 = *(const float4*)(cbx + ((bx +  0) ^ swzX));
      const float4 f1 = *(const float4*)(cbx + ((bx + 16) ^ swzX));
      bf16x8 av;
      av[0] = (short)f2bf(f0.x); av[1] = (short)f2bf(f0.y);
      av[2] = (short)f2bf(f0.z); av[3] = (short)f2bf(f0.w);
      av[4] = (short)f2bf(f1.x); av[5] = (short)f2bf(f1.y);
      av[6] = (short)f2bf(f1.z); av[7] = (short)f2bf(f1.w);
      const bf16x8 bv = *(const bf16x8*)(cbw + ((ks * 64 + quad * 16) ^ swzW));
      acc = __builtin_amdgcn_mfma_f32_16x16x32_bf16(av, bv, acc, 0, 0, 0);
    }
  }

  // C/D layout (verified): col = lane&15 (expert-in-group), row = quad*4+r (token)
#pragma unroll
  for (int r = 0; r < 4; ++r)
    lgs[tg * 16 + quad * 4 + r][eg * 16 + m] = acc[r];
  __syncthreads();

  // Softmax + top-8: wave wv handles tokens 4wv..4wv+3; lane = expert.
  const float rbl = rb[lane];
#pragma unroll
  for (int tt = 0; tt < 4; ++tt) {
    const int t = wv * 4 + tt;
    float l = lgs[t][lane] + rbl;
    const float mx = wred_max(l);
    const float p = expf(l - mx);
    const float inv = 1.f / wred_sum(p);
    float sumw = 0.f, lsel = l;
    float mywk = 0.f;
    int myoff = 0;
#pragma unroll
    for (int k = 0; k < TOPK; ++k) {
      const float mk = wred_max(lsel);
      const unsigned long long bmask = __ballot(lsel == mk);
      const int idx = __ffsll(bmask) - 1;      // tie -> lowest index (matches top_k)
      const float wk = expf(mk - mx) * inv;
      sumw += wk;
      if (lane == k) { mywk = wk; myoff = idx * H; }
      if (lane == idx) lsel = -FLT_MAX;
    }
    const int tgl = t0 + t;
    if (lane == 0) msw_g[tgl] = sumw;
    if (lane < TOPK) {
      mw_g[(size_t)tgl * TOPK + lane] = mywk;
      mi_g[(size_t)tgl * TOPK + lane] = myoff;
    }
  }
}

// ---------------- Combine: barrier-free, LDS-free pure streaming ----------------
// One wave per token. out[t] = x_fp32[t]*sumw + sum_k w_k * Bb[off_k].
__global__ __launch_bounds__(256, 4) void combine_kernel(
    const float* __restrict__ x, const unsigned short* __restrict__ Bb,
    const float* __restrict__ msw_g, const float* __restrict__ mw_g,
    const int* __restrict__ mi_g, float* __restrict__ out) {
  const int tid = threadIdx.x;
  const int wv = tid >> 6, lane = tid & 63;
  const int t = blockIdx.x * 4 + wv;
  const float sw = msw_g[t];
  const float4 w0 = *(const float4*)(mw_g + (size_t)t * TOPK);
  const float4 w1 = *(const float4*)(mw_g + (size_t)t * TOPK + 4);
  const int4  e0 = *(const int4*)(mi_g + (size_t)t * TOPK);
  const int4  e1 = *(const int4*)(mi_g + (size_t)t * TOPK + 4);
  const float wks[8] = {w0.x, w0.y, w0.z, w0.w, w1.x, w1.y, w1.z, w1.w};
  const int   ofs[8] = {e0.x, e0.y, e0.z, e0.w, e1.x, e1.y, e1.z, e1.w};
  const float* xr = x + (size_t)t * H;
  float* orow = out + (size_t)t * H;
#pragma unroll
  for (int ch = 0; ch < 4; ++ch) {
    const int c8 = ch * 512 + lane * 8;
    const float4 xa = *(const float4*)(xr + c8);
    const float4 xb = *(const float4*)(xr + c8 + 4);
    float o[8] = {xa.x * sw, xa.y * sw, xa.z * sw, xa.w * sw,
                  xb.x * sw, xb.y * sw, xb.z * sw, xb.w * sw};
#pragma unroll
    for (int k = 0; k < TOPK; ++k) {
      const bf16x8 bv = *(const bf16x8*)(Bb + ofs[k] + c8);
      const float wk = wks[k];
#pragma unroll
      for (int i = 0; i < 8; ++i) o[i] += wk * bf2f((unsigned short)bv[i]);
    }
    *(float4*)(orow + c8)     = make_float4(o[0], o[1], o[2], o[3]);
    *(float4*)(orow + c8 + 4) = make_float4(o[4], o[5], o[6], o[7]);
  }
}

// ---------------- Fallback fused kernel (no-workspace path) ----------------
__global__ __launch_bounds__(NT, 8) void moe_kernel(
    const float* __restrict__ x, const float* __restrict__ W,
    const float* __restrict__ rb, const float* __restrict__ eb,
    float* __restrict__ out) {
  __shared__ unsigned short xl[TT][H + 8];
  __shared__ float lgp[2][TT][E + 1];
  __shared__ float msw[TT];
  __shared__ float mw[TT][TOPK];
  __shared__ int   mi[TT][TOPK];

  const int tid = threadIdx.x;
  const int t0  = blockIdx.x * TT;
  const int wv = tid >> 6, lane = tid & 63, quad = lane >> 4, m = lane & 15;

  {
    const float* row = x + (size_t)(t0 + wv) * H;
#pragma unroll
    for (int i = 0; i < 8; ++i) {
      const int c = (i * 64 + lane) * 4;
      float4 a = *(const float4*)(row + c);
      us4 ra;
      ra[0] = f2bf(a.x); ra[1] = f2bf(a.y); ra[2] = f2bf(a.z); ra[3] = f2bf(a.w);
      *(us4*)&xl[wv][c] = ra;
    }
  }
  __syncthreads();

  {
    const int eg = wv & 3, kh = wv >> 2;
    const int e = eg * 16 + m;
    const int k0 = kh * (H / 2);
    f32x4 acc = {0.f, 0.f, 0.f, 0.f};
    const unsigned short* xp = &xl[m & 7][k0 + quad * 8];
    const float* wpp = W + (size_t)e * H + k0 + quad * 8;
#pragma unroll 4
    for (int it = 0; it < H / 64; ++it) {
      bf16x8 av = *(const bf16x8*)(xp + it * 32);
      float4 p = *(const float4*)(wpp + it * 32);
      float4 q = *(const float4*)(wpp + it * 32 + 4);
      bf16x8 bv;
      bv[0] = (short)f2bf(p.x); bv[1] = (short)f2bf(p.y);
      bv[2] = (short)f2bf(p.z); bv[3] = (short)f2bf(p.w);
      bv[4] = (short)f2bf(q.x); bv[5] = (short)f2bf(q.y);
      bv[6] = (short)f2bf(q.z); bv[7] = (short)f2bf(q.w);
      acc = __builtin_amdgcn_mfma_f32_16x16x32_bf16(av, bv, acc, 0, 0, 0);
    }
#pragma unroll
    for (int r = 0; r < 4; ++r) {
      const int row = quad * 4 + r;
      if (row < TT) lgp[kh][row][eg * 16 + m] = acc[r];
    }
  }
  __syncthreads();

  {
    const int t = wv;
    float l = lgp[0][t][lane] + lgp[1][t][lane] + rb[lane];
    const float mx = wred_max(l);
    const float p = expf(l - mx);
    const float inv = 1.f / wred_sum(p);
    float sumw = 0.f;
    float lsel = l;
#pragma unroll
    for (int k = 0; k < TOPK; ++k) {
      const float mk = wred_max(lsel);
      const unsigned long long b = __ballot(lsel == mk);
      const int idx = __ffsll(b) - 1;
      const float wk = expf(mk - mx) * inv;
      sumw += wk;
      if (lane == 0) { mw[t][k] = wk; mi[t][k] = idx * H; }
      if (lane == idx) lsel = -FLT_MAX;
    }
    if (lane == 0) msw[t] = sumw;
  }
  __syncthreads();

  {
    const int tg = tid >> 8;
    const int c8 = (tid & 255) * 8;
    const float* ebase = eb + c8;
#pragma unroll 1
    for (int tt = 0; tt < TT / 2; ++tt) {
      const int t = tg * (TT / 2) + tt;
      const float sw = msw[t];
      const float4 w0 = *(const float4*)&mw[t][0];
      const float4 w1 = *(const float4*)&mw[t][4];
      const int4  e0 = *(const int4*)&mi[t][0];
      const int4  e1 = *(const int4*)&mi[t][4];
      const float wks[8] = {w0.x, w0.y, w0.z, w0.w, w1.x, w1.y, w1.z, w1.w};
      const int   ofs[8] = {e0.x, e0.y, e0.z, e0.w, e1.x, e1.y, e1.z, e1.w};
      bf16x8 xv = *(const bf16x8*)&xl[t][c8];
      float o[8];
#pragma unroll
      for (int i = 0; i < 8; ++i) o[i] = bf2f((unsigned short)xv[i]) * sw;
#pragma unroll
      for (int k = 0; k < TOPK; ++k) {
        const float wk = wks[k];
        const float* p = ebase + ofs[k];
        float4 p0 = *(const float4*)p;
        float4 p1 = *(const float4*)(p + 4);
        o[0] += wk * p0.x; o[1] += wk * p0.y; o[2] += wk * p0.z; o[3] += wk * p0.w;
        o[4] += wk * p1.x; o[5] += wk * p1.y; o[6] += wk * p1.z; o[7] += wk * p1.w;
      }
      float* op = out + (size_t)(t0 + t) * H + c8;
      *(float4*)op       = make_float4(o[0], o[1], o[2], o[3]);
      *(float4*)(op + 4) = make_float4(o[4], o[5], o[6], o[7]);
    }
  }
}

extern "C" void kernel_launch(void* const* d_in, const int* in_sizes, int n_in,
                              void* d_out, int out_size, void* d_ws, size_t ws_size,
                              hipStream_t stream) {
  const float* x  = (const float*)d_in[0];
  const float* W  = (const float*)d_in[1];
  const float* rb = (const float*)d_in[2];
  const float* eb = (const float*)d_in[3];
  float* out = (float*)d_out;

  const int T = in_sizes[0] / H;     // 16384
  const size_t szW = (size_t)E * H * sizeof(unsigned short);        // 256 KB
  const size_t meta_sz = (size_t)T * 4 + (size_t)T * TOPK * 4 * 2;  // ~1.06 MB
  const size_t need = 2 * szW + meta_sz;

  if (ws_size >= need) {
    unsigned short* Wb = (unsigned short*)d_ws;
    unsigned short* Bb = Wb + (size_t)E * H;
    float* msw_g = (float*)(Bb + (size_t)E * H);
    float* mw_g  = msw_g + T;
    int*   mi_g  = (int*)(mw_g + (size_t)T * TOPK);
    cvt_kernel<<<(2 * E * H) / (256 * 4), 256, 0, stream>>>(W, eb, Wb, Bb);
    router_kernel<<<T / RTT, 512, 0, stream>>>(x, Wb, rb, msw_g, mw_g, mi_g);
    combine_kernel<<<T / 4, 256, 0, stream>>>(x, Bb, msw_g, mw_g, mi_g, out);
  } else {
    moe_kernel<<<T / TT, NT, 0, stream>>>(x, W, rb, eb, out);
  }
}